// Round 7
// baseline (15.916 us; speedup 1.0000x reference)
//
#include <hip/hip_runtime.h>
#include <hip/hip_bf16.h>

// Problem: B=8, L=4096, H=1024, K=512
// out[b,s,t] = col[b,s] = dot(seq[b, src_pos[b][s], :], w[:H])
//                       + dot(seq[b, tgt_pos[b][s], :], w[H:]) + bias
// Single dispatch, max-occupancy layout: 2048 blocks x 256 threads (4 waves).
// Block owns 2 (b,s) pairs; each wave handles ONE row (src xor tgt) -> 8192
// waves = 32 waves/CU (occupancy cap). Partials pair up through LDS; both
// waves of a pair co-write the 2KB broadcast output row.

#define L_DIM 4096
#define H_DIM 1024
#define K_DIM 512
#define B_DIM 8
#define PACKED_K (K_DIM | (K_DIM << 16))

typedef float f32x4 __attribute__((ext_vector_type(4)));

// 4 bytes (any-nonzero) -> 4-bit movemask, robust to 0/1 or 0/255 encodings
__device__ __forceinline__ unsigned nib4(unsigned w) {
    unsigned x = w | (w >> 4); x |= x >> 2; x |= x >> 1; x &= 0x01010101u;
    return ((x * 0x01020408u) >> 24) & 0xFu;
}
__device__ __forceinline__ unsigned mask16b(uint4 u) {
    return nib4(u.x) | (nib4(u.y) << 4) | (nib4(u.z) << 8) | (nib4(u.w) << 12);
}
// position of n-th (0-based) set bit of m (<=16 bits)
__device__ __forceinline__ int nth16(unsigned m, int n) {
    int pos = 0, c;
    c = __popc(m & 0xFFu); if (n >= c) { n -= c; pos += 8; m >>= 8; }
    c = __popc(m & 0xFu);  if (n >= c) { n -= c; pos += 4; m >>= 4; }
    c = __popc(m & 0x3u);  if (n >= c) { n -= c; pos += 2; m >>= 2; }
    c = (int)(m & 1u);     if (n >= c) { pos += 1; }
    return pos;
}

__global__ __launch_bounds__(256) void fused_kernel(
    const float* __restrict__ seq,
    const void* __restrict__ smask, const void* __restrict__ tmask,
    const float* __restrict__ weight, const float* __restrict__ bias,
    float* __restrict__ out)
{
    const int tid  = threadIdx.x;      // 0..255
    const int wid  = tid >> 6;         // wave in block, 0..3
    const int lane = tid & 63;
    const int bb   = blockIdx.x;       // 0..2047
    const int b    = bb >> 8;          // batch (256 blocks per batch)
    const int sg   = (bb & 255) << 1;  // base s of this block's 2 ranks
    const int p    = wid >> 1;         // pair 0/1  -> s = sg + p
    const int r    = wid & 1;          // role: 0 = src row, 1 = tgt row

    __shared__ int wtot[4];
    __shared__ int posLds[4];          // [0..1]=src pos(p), [2..3]=tgt pos(p)
    __shared__ float part[4];

    // ---- cooperative probe: thread covers bytes [tid*16, tid*16+16) ----
    const uint4* sb = (const uint4*)((const unsigned char*)smask + (size_t)b * L_DIM);
    const uint4* tb = (const uint4*)((const unsigned char*)tmask + (size_t)b * L_DIM);
    unsigned mS = mask16b(sb[tid]);
    unsigned mT = mask16b(tb[tid]);
    int packed = __popc(mS) | (__popc(mT) << 16);

    int x = packed;                     // wave-inclusive scan (packed both masks)
#pragma unroll
    for (int off = 1; off < 64; off <<= 1) {
        int y = __shfl_up(x, off, 64);
        if (lane >= off) x += y;
    }
    if (lane == 63) wtot[wid] = x;
    __syncthreads();
    int off_ = 0, tot = 0;
#pragma unroll
    for (int w = 0; w < 4; ++w) { int v = wtot[w]; tot += v; if (w < wid) off_ += v; }
    x += off_;

    if (tot != PACKED_K) {              // block-uniform: masks are int32, redo
        __syncthreads();                // protect wtot before rewrite
        const uint4* si = (const uint4*)((const unsigned*)smask + (size_t)b * L_DIM) + tid * 4;
        const uint4* ti = (const uint4*)((const unsigned*)tmask + (size_t)b * L_DIM) + tid * 4;
        mS = 0u; mT = 0u;
#pragma unroll
        for (int j = 0; j < 4; ++j) {
            uint4 u = si[j], v = ti[j];
            const int base = j * 4;
            mS |= (((u.x != 0) ? 1u : 0u) << base) | (((u.y != 0) ? 1u : 0u) << (base + 1))
                | (((u.z != 0) ? 1u : 0u) << (base + 2)) | (((u.w != 0) ? 1u : 0u) << (base + 3));
            mT |= (((v.x != 0) ? 1u : 0u) << base) | (((v.y != 0) ? 1u : 0u) << (base + 1))
                | (((v.z != 0) ? 1u : 0u) << (base + 2)) | (((v.w != 0) ? 1u : 0u) << (base + 3));
        }
        packed = __popc(mS) | (__popc(mT) << 16);
        x = packed;
#pragma unroll
        for (int off = 1; off < 64; off <<= 1) {
            int y = __shfl_up(x, off, 64);
            if (lane >= off) x += y;
        }
        if (lane == 63) wtot[wid] = x;
        __syncthreads();
        off_ = 0;
#pragma unroll
        for (int w = 0; w < 4; ++w) { int v = wtot[w]; if (w < wid) off_ += v; }
        x += off_;
    }

    const int exc  = x - packed;        // exclusive prefix, packed
    const int excS = exc & 0xffff, excT = exc >> 16;  // fields never carry (<=512)
    const int cntS = __popc(mS), cntT = __popc(mT);
#pragma unroll
    for (int j = 0; j < 2; ++j) {
        const int s = sg + j;
        if (s >= excS && s < excS + cntS) posLds[j]     = tid * 16 + nth16(mS, s - excS);
        if (s >= excT && s < excT + cntT) posLds[2 + j] = tid * 16 + nth16(mT, s - excT);
    }
    __syncthreads();

    // ---- one row per wave: dot(row, weight_half) ----
    const int pos = posLds[r * 2 + p];
    const float4* __restrict__ row = (const float4*)(seq + ((size_t)b * L_DIM + pos) * H_DIM);
    const float4* __restrict__ wv  = (const float4*)(weight + r * H_DIM);  // L1-hot

    float acc = 0.f;
#pragma unroll
    for (int j = 0; j < 4; ++j) {
        const int i = lane + 64 * j;
        float4 a = row[i], wa = wv[i];
        acc += a.x * wa.x + a.y * wa.y + a.z * wa.z + a.w * wa.w;
    }
#pragma unroll
    for (int off = 32; off; off >>= 1) acc += __shfl_xor(acc, off, 64);

    if (lane == 0) part[wid] = acc;
    __syncthreads();

    // ---- pair combine + co-write the 2KB output row ----
    const float col = part[2 * p] + part[2 * p + 1] + bias[0];
    const f32x4 v = {col, col, col, col};
    f32x4* orow = (f32x4*)(out + ((size_t)(b * K_DIM + sg + p)) * K_DIM);
    orow[r * 64 + lane] = v;            // each wave writes half the row
}

extern "C" void kernel_launch(void* const* d_in, const int* in_sizes, int n_in,
                              void* d_out, int out_size, void* d_ws, size_t ws_size,
                              hipStream_t stream) {
    const float* seq    = (const float*)d_in[0];
    const void*  smask  = d_in[1];
    const void*  tmask  = d_in[2];
    const float* weight = (const float*)d_in[3];
    const float* bias   = (const float*)d_in[4];
    float* out = (float*)d_out;
    (void)d_ws; (void)ws_size;

    fused_kernel<<<2048, 256, 0, stream>>>(seq, smask, tmask, weight, bias, out);
}